// Round 7
// baseline (467.457 us; speedup 1.0000x reference)
//
#include <hip/hip_runtime.h>

#define N_NODES 8192
#define IN_F 512
#define OUT_F 64
#define LOG2E 1.4426950408889634f

typedef short bf16x8 __attribute__((ext_vector_type(8)));
typedef float f32x4 __attribute__((ext_vector_type(4)));

// K1: h = input @ W. 512 blocks x 4 waves; each wave computes 4 rows
// (2 blocks/CU, 8 waves/CU). W reads are lane-striped (L2-resident);
// input-row loads are wave-uniform. Writes hT (bf16, transposed via LDS)
// and fsrcL/fdstL (pre-scaled by log2e).
// No global-max pass: |fs+fd| <= ~64 => p <= 2^92, row sums <= ~4e31 —
// inside f32 range; num/den share scale so the quotient is unchanged
// up to rounding (validated R3: absmax identical to max-subtracted).
__global__ __launch_bounds__(256) void k_gemm(const float* __restrict__ input,
                                              const float* __restrict__ W,
                                              const float* __restrict__ a,
                                              unsigned short* __restrict__ hT,
                                              float* __restrict__ fsrcL,
                                              float* __restrict__ fdstL) {
  const int lane = threadIdx.x & 63;
  const int wv = threadIdx.x >> 6;
  const int r0 = blockIdx.x * 16;
  const int rw = r0 + wv * 4;
  const int c = lane;
  float acc[4] = {0.f, 0.f, 0.f, 0.f};
  const float* Wc = W + c;
  for (int k = 0; k < IN_F; k += 4) {
    float w0 = Wc[(k + 0) * OUT_F];
    float w1 = Wc[(k + 1) * OUT_F];
    float w2 = Wc[(k + 2) * OUT_F];
    float w3 = Wc[(k + 3) * OUT_F];
#pragma unroll
    for (int r = 0; r < 4; r++) {
      float4 x = *(const float4*)(input + (size_t)(rw + r) * IN_F + k);
      acc[r] += x.x * w0 + x.y * w1 + x.z * w2 + x.w * w3;
    }
  }
#pragma unroll
  for (int r = 0; r < 4; r++) {
    float vs = acc[r] * a[c];
    float vd = acc[r] * a[OUT_F + c];
#pragma unroll
    for (int off = 32; off > 0; off >>= 1) {
      vs += __shfl_xor(vs, off, 64);
      vd += __shfl_xor(vd, off, 64);
    }
    if (lane == 0) {
      fsrcL[rw + r] = vs * LOG2E;
      fdstL[rw + r] = vd * LOG2E;
    }
  }
  // transpose through LDS (padded): hT[c][r0..r0+16) as 16 packed bf16
  __shared__ float hs[16][65];
#pragma unroll
  for (int r = 0; r < 4; r++) hs[wv * 4 + r][c] = acc[r];
  __syncthreads();
  {
    const int cc = threadIdx.x >> 2;  // 0..63
    const int q = threadIdx.x & 3;    // row-quad
    unsigned uu[4];
#pragma unroll
    for (int rr = 0; rr < 4; rr++)
      uu[rr] = __float_as_uint(hs[q * 4 + rr][cc]) + 0x8000u;
    uint2 pk;
    pk.x = __builtin_amdgcn_perm(uu[1], uu[0], 0x07060302u);
    pk.y = __builtin_amdgcn_perm(uu[3], uu[2], 0x07060302u);
    *(uint2*)(hT + (size_t)cc * N_NODES + r0 + q * 4) = pk;
  }
}

// K2: fused attention, single pass (R3 structure, two reverts):
//  - plain int4 adj loads (nt removed — R2/R3 implicated it)
//  - R0's unhoisted LeakyReLU arithmetic (hoist removed — present in
//    every regressed variant R1/R2/R3, absent in every good one)
// Grid = 512 blocks x 8 waves; each block owns 16 rows x all 8192 cols
// (each wave 1024 cols = 16 windows of 64). Block-level LDS reduction,
// then divide + ELU + final store — no partials, no merge kernel.
__global__ __launch_bounds__(512) void k_attn(const int* __restrict__ adj,
                                              const unsigned short* __restrict__ hT,
                                              const float* __restrict__ fsrcL,
                                              const float* __restrict__ fdstL,
                                              float* __restrict__ out) {
  const int lane = threadIdx.x & 63;
  const int wv = threadIdx.x >> 6;  // 0..7
  const int i0 = blockIdx.x * 16;
  const int m = lane & 15;  // A-row / B-col index
  const int g = lane >> 4;  // k-group 0..3

  const float fs = fsrcL[i0 + m];  // log2-scaled

  f32x4 acc0{}, acc1{}, acc2{}, acc3{};
  float lpart = 0.f;

  const int* adjrow = adj + (size_t)(i0 + m) * N_NODES;
  const unsigned short* hT0 = hT + (size_t)m * N_NODES;

  const int jbeg = wv * (N_NODES / 8);
  for (int j0 = jbeg; j0 < jbeg + (N_NODES / 8); j0 += 64) {
    const int jb0 = j0 + g * 8;
    const int jb1 = j0 + 32 + g * 8;
    // ---- all loads for this 64-col window ----
    int4 a00 = *(const int4*)(adjrow + jb0);
    int4 a01 = *(const int4*)(adjrow + jb0 + 4);
    int4 a10 = *(const int4*)(adjrow + jb1);
    int4 a11 = *(const int4*)(adjrow + jb1 + 4);
    float4 d00 = *(const float4*)(fdstL + jb0);
    float4 d01 = *(const float4*)(fdstL + jb0 + 4);
    float4 d10 = *(const float4*)(fdstL + jb1);
    float4 d11 = *(const float4*)(fdstL + jb1 + 4);
    bf16x8 b00 = *(const bf16x8*)(hT0 + jb0);
    bf16x8 b01 = *(const bf16x8*)(hT0 + (size_t)16 * N_NODES + jb0);
    bf16x8 b02 = *(const bf16x8*)(hT0 + (size_t)32 * N_NODES + jb0);
    bf16x8 b03 = *(const bf16x8*)(hT0 + (size_t)48 * N_NODES + jb0);
    bf16x8 b10 = *(const bf16x8*)(hT0 + jb1);
    bf16x8 b11 = *(const bf16x8*)(hT0 + (size_t)16 * N_NODES + jb1);
    bf16x8 b12 = *(const bf16x8*)(hT0 + (size_t)32 * N_NODES + jb1);
    bf16x8 b13 = *(const bf16x8*)(hT0 + (size_t)48 * N_NODES + jb1);
    // ---- compute s=0 ----
    {
      const int av[8] = {a00.x, a00.y, a00.z, a00.w, a01.x, a01.y, a01.z, a01.w};
      const float dv[8] = {d00.x, d00.y, d00.z, d00.w, d01.x, d01.y, d01.z, d01.w};
      unsigned u[8];
#pragma unroll
      for (int t = 0; t < 8; t++) {
        float x = fs + dv[t];
        float y = fmaxf(x, 0.2f * x);
        float p = __builtin_amdgcn_exp2f(y);
        p = av[t] ? p : 0.0f;
        lpart += p;
        u[t] = __float_as_uint(p) + 0x8000u;
      }
      union { unsigned w[4]; bf16x8 v; } pc;
      pc.w[0] = __builtin_amdgcn_perm(u[1], u[0], 0x07060302u);
      pc.w[1] = __builtin_amdgcn_perm(u[3], u[2], 0x07060302u);
      pc.w[2] = __builtin_amdgcn_perm(u[5], u[4], 0x07060302u);
      pc.w[3] = __builtin_amdgcn_perm(u[7], u[6], 0x07060302u);
      acc0 = __builtin_amdgcn_mfma_f32_16x16x32_bf16(pc.v, b00, acc0, 0, 0, 0);
      acc1 = __builtin_amdgcn_mfma_f32_16x16x32_bf16(pc.v, b01, acc1, 0, 0, 0);
      acc2 = __builtin_amdgcn_mfma_f32_16x16x32_bf16(pc.v, b02, acc2, 0, 0, 0);
      acc3 = __builtin_amdgcn_mfma_f32_16x16x32_bf16(pc.v, b03, acc3, 0, 0, 0);
    }
    // ---- compute s=1 ----
    {
      const int av[8] = {a10.x, a10.y, a10.z, a10.w, a11.x, a11.y, a11.z, a11.w};
      const float dv[8] = {d10.x, d10.y, d10.z, d10.w, d11.x, d11.y, d11.z, d11.w};
      unsigned u[8];
#pragma unroll
      for (int t = 0; t < 8; t++) {
        float x = fs + dv[t];
        float y = fmaxf(x, 0.2f * x);
        float p = __builtin_amdgcn_exp2f(y);
        p = av[t] ? p : 0.0f;
        lpart += p;
        u[t] = __float_as_uint(p) + 0x8000u;
      }
      union { unsigned w[4]; bf16x8 v; } pc;
      pc.w[0] = __builtin_amdgcn_perm(u[1], u[0], 0x07060302u);
      pc.w[1] = __builtin_amdgcn_perm(u[3], u[2], 0x07060302u);
      pc.w[2] = __builtin_amdgcn_perm(u[5], u[4], 0x07060302u);
      pc.w[3] = __builtin_amdgcn_perm(u[7], u[6], 0x07060302u);
      acc0 = __builtin_amdgcn_mfma_f32_16x16x32_bf16(pc.v, b10, acc0, 0, 0, 0);
      acc1 = __builtin_amdgcn_mfma_f32_16x16x32_bf16(pc.v, b11, acc1, 0, 0, 0);
      acc2 = __builtin_amdgcn_mfma_f32_16x16x32_bf16(pc.v, b12, acc2, 0, 0, 0);
      acc3 = __builtin_amdgcn_mfma_f32_16x16x32_bf16(pc.v, b13, acc3, 0, 0, 0);
    }
  }

  // l: reduce across the 4 k-groups (lanes sharing m)
  lpart += __shfl_xor(lpart, 16, 64);
  lpart += __shfl_xor(lpart, 32, 64);

  __shared__ float accbuf[8][16][64];
  __shared__ float lbuf[8][16];
#pragma unroll
  for (int r = 0; r < 4; r++) {
    accbuf[wv][g * 4 + r][0 + m]  = acc0[r];
    accbuf[wv][g * 4 + r][16 + m] = acc1[r];
    accbuf[wv][g * 4 + r][32 + m] = acc2[r];
    accbuf[wv][g * 4 + r][48 + m] = acc3[r];
  }
  if (lane < 16) lbuf[wv][lane] = lpart;
  __syncthreads();

  // 16 rows x 64 cols = 1024 outputs, 2 per thread: merge + divide + ELU
#pragma unroll
  for (int q = 0; q < 2; q++) {
    int idx = q * 512 + threadIdx.x;
    int r = idx >> 6, c = idx & 63;
    float ssum = 0.f, ltot = 0.f;
#pragma unroll
    for (int w = 0; w < 8; w++) {
      ssum += accbuf[w][r][c];
      ltot += lbuf[w][r];
    }
    float v = ssum / ltot;
    out[(size_t)(i0 + r) * OUT_F + c] =
        v > 0.f ? v : __builtin_amdgcn_exp2f(v * LOG2E) - 1.f;
  }
}

extern "C" void kernel_launch(void* const* d_in, const int* in_sizes, int n_in,
                              void* d_out, int out_size, void* d_ws, size_t ws_size,
                              hipStream_t stream) {
  const float* input = (const float*)d_in[0];
  const int* adj = (const int*)d_in[1];
  const float* W = (const float*)d_in[2];
  const float* a = (const float*)d_in[3];
  float* out = (float*)d_out;

  char* ws = (char*)d_ws;
  unsigned short* hT = (unsigned short*)ws;              // 1 MB
  float* fsrcL = (float*)(ws + (1u << 20));              // 32 KB
  float* fdstL = (float*)(ws + (1u << 20) + 32 * 1024);  // 32 KB

  k_gemm<<<N_NODES / 16, 256, 0, stream>>>(input, W, a, hT, fsrcL, fdstL);
  k_attn<<<N_NODES / 16, 512, 0, stream>>>(adj, hT, fsrcL, fdstL, out);
}

// Round 8
// 442.196 us; speedup vs baseline: 1.0571x; 1.0571x over previous
//
#include <hip/hip_runtime.h>

#define N_NODES 8192
#define IN_F 512
#define OUT_F 64
#define LOG2E 1.4426950408889634f
#define JSPLIT 8

typedef short bf16x8 __attribute__((ext_vector_type(8)));
typedef float f32x4 __attribute__((ext_vector_type(4)));

// K1: h = input @ W. 512 blocks x 4 waves; each wave computes 4 rows
// (2 blocks/CU, 8 waves/CU). W reads are lane-striped (L2-resident);
// input-row loads are wave-uniform. Writes hT (bf16, transposed via LDS)
// and fsrcL/fdstL (pre-scaled by log2e).
__global__ __launch_bounds__(256) void k_gemm(const float* __restrict__ input,
                                              const float* __restrict__ W,
                                              const float* __restrict__ a,
                                              unsigned short* __restrict__ hT,
                                              float* __restrict__ fsrcL,
                                              float* __restrict__ fdstL) {
  const int lane = threadIdx.x & 63;
  const int wv = threadIdx.x >> 6;
  const int r0 = blockIdx.x * 16;
  const int rw = r0 + wv * 4;
  const int c = lane;
  float acc[4] = {0.f, 0.f, 0.f, 0.f};
  const float* Wc = W + c;
  for (int k = 0; k < IN_F; k += 4) {
    float w0 = Wc[(k + 0) * OUT_F];
    float w1 = Wc[(k + 1) * OUT_F];
    float w2 = Wc[(k + 2) * OUT_F];
    float w3 = Wc[(k + 3) * OUT_F];
#pragma unroll
    for (int r = 0; r < 4; r++) {
      float4 x = *(const float4*)(input + (size_t)(rw + r) * IN_F + k);
      acc[r] += x.x * w0 + x.y * w1 + x.z * w2 + x.w * w3;
    }
  }
#pragma unroll
  for (int r = 0; r < 4; r++) {
    float vs = acc[r] * a[c];
    float vd = acc[r] * a[OUT_F + c];
#pragma unroll
    for (int off = 32; off > 0; off >>= 1) {
      vs += __shfl_xor(vs, off, 64);
      vd += __shfl_xor(vd, off, 64);
    }
    if (lane == 0) {
      fsrcL[rw + r] = vs * LOG2E;
      fdstL[rw + r] = vd * LOG2E;
    }
  }
  // transpose through LDS (padded): hT[c][r0..r0+16) as 16 packed bf16
  __shared__ float hs[16][65];
#pragma unroll
  for (int r = 0; r < 4; r++) hs[wv * 4 + r][c] = acc[r];
  __syncthreads();
  {
    const int cc = threadIdx.x >> 2;  // 0..63
    const int q = threadIdx.x & 3;    // row-quad
    unsigned uu[4];
#pragma unroll
    for (int rr = 0; rr < 4; rr++)
      uu[rr] = __float_as_uint(hs[q * 4 + rr][cc]) + 0x8000u;
    uint2 pk;
    pk.x = __builtin_amdgcn_perm(uu[1], uu[0], 0x07060302u);
    pk.y = __builtin_amdgcn_perm(uu[3], uu[2], 0x07060302u);
    *(uint2*)(hT + (size_t)cc * N_NODES + r0 + q * 4) = pk;
  }
}

// K2: attention partials. Grid = 512 row-blocks x JSPLIT j-slabs (4096
// blocks, 4 waves each) — the proven split structure (R0/R4/R6).
// CHANGE vs R0 (single variable): NO max-subtraction softmax, so the
// serializing 1-block k_max dispatch is deleted (4 -> 3 dispatches).
// Numerics validated in R3/R7: |fs+fd|*log2e <= ~92 => p <= 2^92,
// row sums <= ~4e31 — inside f32/bf16 exponent range; num/den share
// the same scale so the quotient is unchanged up to rounding (absmax
// was bit-identical 0.0625 across with-ML and no-ML runs).
// Writes num[js][i][c], den[js][i]; k_merge divides + ELU.
__global__ __launch_bounds__(256) void k_attn(const int* __restrict__ adj,
                                              const unsigned short* __restrict__ hT,
                                              const float* __restrict__ fsrcL,
                                              const float* __restrict__ fdstL,
                                              float* __restrict__ num,
                                              float* __restrict__ den) {
  const int lane = threadIdx.x & 63;
  const int wv = threadIdx.x >> 6;  // 0..3
  const int rb = blockIdx.x >> 3;
  const int js = blockIdx.x & 7;
  const int i0 = rb * 16;
  const int m = lane & 15;  // A-row / B-col index
  const int g = lane >> 4;  // k-group 0..3

  const float fs = fsrcL[i0 + m];  // log2-scaled

  f32x4 acc0{}, acc1{}, acc2{}, acc3{};
  float lpart = 0.f;

  const int* adjrow = adj + (size_t)(i0 + m) * N_NODES;
  const unsigned short* hT0 = hT + (size_t)m * N_NODES;

  const int jbeg = js * (N_NODES / JSPLIT) + wv * 256;
  for (int j0 = jbeg; j0 < jbeg + 256; j0 += 64) {
    const int jb0 = j0 + g * 8;
    const int jb1 = j0 + 32 + g * 8;
    // ---- all loads for this 64-col window ----
    int4 a00 = *(const int4*)(adjrow + jb0);
    int4 a01 = *(const int4*)(adjrow + jb0 + 4);
    int4 a10 = *(const int4*)(adjrow + jb1);
    int4 a11 = *(const int4*)(adjrow + jb1 + 4);
    float4 d00 = *(const float4*)(fdstL + jb0);
    float4 d01 = *(const float4*)(fdstL + jb0 + 4);
    float4 d10 = *(const float4*)(fdstL + jb1);
    float4 d11 = *(const float4*)(fdstL + jb1 + 4);
    bf16x8 b00 = *(const bf16x8*)(hT0 + jb0);
    bf16x8 b01 = *(const bf16x8*)(hT0 + (size_t)16 * N_NODES + jb0);
    bf16x8 b02 = *(const bf16x8*)(hT0 + (size_t)32 * N_NODES + jb0);
    bf16x8 b03 = *(const bf16x8*)(hT0 + (size_t)48 * N_NODES + jb0);
    bf16x8 b10 = *(const bf16x8*)(hT0 + jb1);
    bf16x8 b11 = *(const bf16x8*)(hT0 + (size_t)16 * N_NODES + jb1);
    bf16x8 b12 = *(const bf16x8*)(hT0 + (size_t)32 * N_NODES + jb1);
    bf16x8 b13 = *(const bf16x8*)(hT0 + (size_t)48 * N_NODES + jb1);
    // ---- compute s=0 ----
    {
      const int av[8] = {a00.x, a00.y, a00.z, a00.w, a01.x, a01.y, a01.z, a01.w};
      const float dv[8] = {d00.x, d00.y, d00.z, d00.w, d01.x, d01.y, d01.z, d01.w};
      unsigned u[8];
#pragma unroll
      for (int t = 0; t < 8; t++) {
        float x = fs + dv[t];
        float y = fmaxf(x, 0.2f * x);
        float p = __builtin_amdgcn_exp2f(y);
        p = av[t] ? p : 0.0f;
        lpart += p;
        u[t] = __float_as_uint(p) + 0x8000u;
      }
      union { unsigned w[4]; bf16x8 v; } pc;
      pc.w[0] = __builtin_amdgcn_perm(u[1], u[0], 0x07060302u);
      pc.w[1] = __builtin_amdgcn_perm(u[3], u[2], 0x07060302u);
      pc.w[2] = __builtin_amdgcn_perm(u[5], u[4], 0x07060302u);
      pc.w[3] = __builtin_amdgcn_perm(u[7], u[6], 0x07060302u);
      acc0 = __builtin_amdgcn_mfma_f32_16x16x32_bf16(pc.v, b00, acc0, 0, 0, 0);
      acc1 = __builtin_amdgcn_mfma_f32_16x16x32_bf16(pc.v, b01, acc1, 0, 0, 0);
      acc2 = __builtin_amdgcn_mfma_f32_16x16x32_bf16(pc.v, b02, acc2, 0, 0, 0);
      acc3 = __builtin_amdgcn_mfma_f32_16x16x32_bf16(pc.v, b03, acc3, 0, 0, 0);
    }
    // ---- compute s=1 ----
    {
      const int av[8] = {a10.x, a10.y, a10.z, a10.w, a11.x, a11.y, a11.z, a11.w};
      const float dv[8] = {d10.x, d10.y, d10.z, d10.w, d11.x, d11.y, d11.z, d11.w};
      unsigned u[8];
#pragma unroll
      for (int t = 0; t < 8; t++) {
        float x = fs + dv[t];
        float y = fmaxf(x, 0.2f * x);
        float p = __builtin_amdgcn_exp2f(y);
        p = av[t] ? p : 0.0f;
        lpart += p;
        u[t] = __float_as_uint(p) + 0x8000u;
      }
      union { unsigned w[4]; bf16x8 v; } pc;
      pc.w[0] = __builtin_amdgcn_perm(u[1], u[0], 0x07060302u);
      pc.w[1] = __builtin_amdgcn_perm(u[3], u[2], 0x07060302u);
      pc.w[2] = __builtin_amdgcn_perm(u[5], u[4], 0x07060302u);
      pc.w[3] = __builtin_amdgcn_perm(u[7], u[6], 0x07060302u);
      acc0 = __builtin_amdgcn_mfma_f32_16x16x32_bf16(pc.v, b10, acc0, 0, 0, 0);
      acc1 = __builtin_amdgcn_mfma_f32_16x16x32_bf16(pc.v, b11, acc1, 0, 0, 0);
      acc2 = __builtin_amdgcn_mfma_f32_16x16x32_bf16(pc.v, b12, acc2, 0, 0, 0);
      acc3 = __builtin_amdgcn_mfma_f32_16x16x32_bf16(pc.v, b13, acc3, 0, 0, 0);
    }
  }

  // l: reduce across the 4 k-groups (lanes sharing m)
  lpart += __shfl_xor(lpart, 16, 64);
  lpart += __shfl_xor(lpart, 32, 64);

  __shared__ float accbuf[4][16][64];
  __shared__ float lbuf[4][16];
#pragma unroll
  for (int r = 0; r < 4; r++) {
    accbuf[wv][g * 4 + r][0 + m]  = acc0[r];
    accbuf[wv][g * 4 + r][16 + m] = acc1[r];
    accbuf[wv][g * 4 + r][32 + m] = acc2[r];
    accbuf[wv][g * 4 + r][48 + m] = acc3[r];
  }
  if (lane < 16) lbuf[wv][lane] = lpart;
  __syncthreads();

#pragma unroll
  for (int q = 0; q < 4; q++) {
    int idx = q * 256 + threadIdx.x;
    int r = idx >> 6, c = idx & 63;
    float ssum = accbuf[0][r][c] + accbuf[1][r][c] + accbuf[2][r][c] + accbuf[3][r][c];
    num[((size_t)js * N_NODES + i0 + r) * OUT_F + c] = ssum;
  }
  if (threadIdx.x < 16) {
    den[(size_t)js * N_NODES + i0 + threadIdx.x] =
        lbuf[0][threadIdx.x] + lbuf[1][threadIdx.x] + lbuf[2][threadIdx.x] + lbuf[3][threadIdx.x];
  }
}

// K3: merge partials, divide, ELU.
__global__ __launch_bounds__(256) void k_merge(const float* __restrict__ num,
                                               const float* __restrict__ den,
                                               float* __restrict__ out) {
  const int idx = blockIdx.x * 256 + threadIdx.x;  // over N*OUT_F
  const int i = idx >> 6;
  float s = 0.f, l = 0.f;
#pragma unroll
  for (int js = 0; js < JSPLIT; js++) {
    s += num[((size_t)js * N_NODES) * OUT_F + idx];
    l += den[(size_t)js * N_NODES + i];
  }
  float v = s / l;
  out[idx] = v > 0.f ? v : __builtin_amdgcn_exp2f(v * LOG2E) - 1.f;
}

extern "C" void kernel_launch(void* const* d_in, const int* in_sizes, int n_in,
                              void* d_out, int out_size, void* d_ws, size_t ws_size,
                              hipStream_t stream) {
  const float* input = (const float*)d_in[0];
  const int* adj = (const int*)d_in[1];
  const float* W = (const float*)d_in[2];
  const float* a = (const float*)d_in[3];
  float* out = (float*)d_out;

  char* ws = (char*)d_ws;
  unsigned short* hT = (unsigned short*)ws;                  // 1 MB
  float* fsrcL = (float*)(ws + (1u << 20));                  // 32 KB
  float* fdstL = (float*)(ws + (1u << 20) + 32 * 1024);      // 32 KB
  float* num = (float*)(ws + (2u << 20));                    // 16 MB
  float* den = (float*)(ws + (20u << 20));                   // 256 KB

  k_gemm<<<N_NODES / 16, 256, 0, stream>>>(input, W, a, hT, fsrcL, fdstL);
  k_attn<<<(N_NODES / 16) * JSPLIT, 256, 0, stream>>>(adj, hT, fsrcL, fdstL, num, den);
  k_merge<<<N_NODES * OUT_F / 256, 256, 0, stream>>>(num, den, out);
}